// Round 17
// baseline (1284.996 us; speedup 1.0000x reference)
//
#include <hip/hip_runtime.h>

// VanillaRNN: BATCH=1024, SEQ=512, HID=512, OUT=10
// h <- tanh(W_hh @ h + W_hx x_t + b_h), 512 steps, then y = W_yh h + b_y.
//
// Round 21: champion (R13, 1208-1217us) + the one untested register-safe
// mechanism: the W-tail is STEP-INVARIANT, so chunk 0's 4 W-frag reads are
// barrier-independent -- issue them in the epilogue, they complete during
// the barrier drain, deleting the loop-head 5-read serial chain (~200cyc).
// Requires dbuf HB + single barrier (proven R5/R7): reads of buf[s&1] and
// writes of buf[s^1&1] don't conflict -> mid-step barrier removed; the end
// barrier orders step-s reads of buf A before step-s+1 writes to buf A.
// wg[4] (16 regs) lives only across the barrier->t=0 window where the
// epilogue's ~30 working regs are dead -> high-water unchanged.
// LDS = 128K WL + 32K HB dbuf = 163840 (full pool).
// Gates: WRITE_SIZE 1024KB (no spill), absmax pass.
//
// ws: [0,1MB) hG (final h, frag-blocked) | [2MB,2.5MB) W A-frags.

#define BATCH 1024
#define SEQT  512
#define HID   512
#define OUTD  10
#define KR    12   // kk-blocks (of K=32) in registers: K=384
#define NKK   16

typedef _Float16 f16;
typedef _Float16 f16x8 __attribute__((ext_vector_type(8)));
typedef _Float16 f16x4 __attribute__((ext_vector_type(4)));
typedef float    f32x4 __attribute__((ext_vector_type(4)));

// W_hh fp32 [H][H] -> fp16 A-fragment layout:
// entry ((g*4+mt)*16+kk)*64+lane = f16x8 of A[m][k],
// m = g*64+mt*16+(lane&15), k = kk*32+((lane>>4)&3)*8+j.
__global__ void wconv_kernel(const float* __restrict__ Whh, f16* __restrict__ frag) {
    int id = blockIdx.x * blockDim.x + threadIdx.x;   // 0..32767
    int lane = id & 63;
    int kk   = (id >> 6) & 15;
    int mt   = (id >> 10) & 3;
    int g    = id >> 12;
    int m = g * 64 + mt * 16 + (lane & 15);
    int k = kk * 32 + ((lane >> 4) & 3) * 8;
    const float* src = Whh + (size_t)m * HID + k;
    f16x8 v;
#pragma unroll
    for (int j = 0; j < 8; ++j) v[j] = (f16)src[j];
    *(f16x8*)(frag + (size_t)id * 8) = v;
}

__device__ __forceinline__ float fast_tanh(float v) {
    v = fminf(fmaxf(v, -15.f), 15.f);
    float e = __expf(2.f * v);
    return (e - 1.f) * __builtin_amdgcn_rcpf(e + 1.f);
}

__global__ __launch_bounds__(512)
__attribute__((amdgpu_waves_per_eu(2, 2)))
void rnn_cu(
    const f16* __restrict__ frag,   // W_hh A-frags (all 16 kk-blocks)
    f16* __restrict__ hG,           // final h, frag-blocked [64][16][64][8]
    const float* __restrict__ x,    // [B][T]
    const float* __restrict__ Whx,  // [H]
    const float* __restrict__ bh)   // [H]
{
    // HB first: short ds offsets (<32 KB) with lane-only addressing.
    __shared__ f16 HB[2][8192];     // double-buffered h, B-frag layout, 32 KB
    __shared__ f16 WL[65536];       // W A-frags kk 12..15, 128 KB

    const int tid  = threadIdx.x;
    const int w    = tid >> 6;       // wave = row-group of 64 rows
    const int lane = tid & 63;
    const int n    = lane & 15;      // batch col within group
    const int q    = lane >> 4;
    const int bg   = blockIdx.x;     // batch group: cols [bg*16, +16)

    // ---- h(0) = 0 (buffer 0 is read at s=0) ----
    {
        f16x8 z;
#pragma unroll
        for (int j = 0; j < 8; ++j) z[j] = (f16)0.f;
        *(f16x8*)&HB[0][tid * 16]     = z;
        *(f16x8*)&HB[0][tid * 16 + 8] = z;
    }

    const f16x8* A = (const f16x8*)frag;

    // ---- LDS W portion: wave w stages its (mt, kk 12..15) frags ----
#pragma unroll
    for (int mt = 0; mt < 4; ++mt)
#pragma unroll
        for (int kkl = 0; kkl < 4; ++kkl) {
            int e = ((w * 4 + mt) * 4 + kkl) * 64 + lane;
            *(f16x8*)&WL[e * 8] = A[((w * 4 + mt) * 16 + (KR + kkl)) * 64 + lane];
        }

    // ---- register W portion: kk 0..11, kk-major, static indices ----
    f16x8 Wr[KR * 4];
#pragma unroll
    for (int kk = 0; kk < KR; ++kk)
#pragma unroll
        for (int mt = 0; mt < 4; ++mt)
            Wr[kk * 4 + mt] = A[((w * 4 + mt) * 16 + kk) * 64 + lane];

    __syncthreads();

    const int b = bg * 16 + n;
    const float* xp = x + (size_t)b * SEQT;

    // ---- prologue: chunk-0 (block 12) W frags resident for s=0 ----
    f16x8 wg[4];
#pragma unroll
    for (int mt = 0; mt < 4; ++mt)
        wg[mt] = *(const f16x8*)&WL[(((w * 4 + mt) * 4 + 0) * 64 + lane) * 8];

#pragma unroll 1
    for (int s = 0; s < SEQT; ++s) {
        const f16* hbr = &HB[s & 1][0];          // read h(s)
        f16*       hbw = &HB[(s & 1) ^ 1][0];    // write h(s+1)
        float xv = xp[s];

        f32x4 acc[4] = {{0,0,0,0},{0,0,0,0},{0,0,0,0},{0,0,0,0}};

        // ---- interleaved schedule: one LDS-W block per 4-slot chunk;
        //      chunk t=0's W frags (wg) were issued before the barrier ----
#pragma unroll
        for (int t = 0; t < NKK; ++t) {
            constexpr int ord[NKK] = {12, 0, 1, 2, 13, 3, 4, 5,
                                      14, 6, 7, 8, 15, 9, 10, 11};
            const int kb = ord[t];
            f16x8 bf = *(const f16x8*)&hbr[(kb * 64 + lane) * 8];
            if (t == 0) {               // W pre-issued across the barrier
#pragma unroll
                for (int mt = 0; mt < 4; ++mt)
                    acc[mt] = __builtin_amdgcn_mfma_f32_16x16x32_f16(
                        wg[mt], bf, acc[mt], 0, 0, 0);
            } else if ((t & 3) == 0) {  // LDS-W chunk, inline reads
                const int kkl = t >> 2;
#pragma unroll
                for (int mt = 0; mt < 4; ++mt) {
                    f16x8 a = *(const f16x8*)&WL[(((w * 4 + mt) * 4 + kkl) * 64 + lane) * 8];
                    acc[mt] = __builtin_amdgcn_mfma_f32_16x16x32_f16(
                        a, bf, acc[mt], 0, 0, 0);
                }
            } else {                    // register-W chunk
                const int rb = t - 1 - (t >> 2);
#pragma unroll
                for (int mt = 0; mt < 4; ++mt)
                    acc[mt] = __builtin_amdgcn_mfma_f32_16x16x32_f16(
                        Wr[rb * 4 + mt], bf, acc[mt], 0, 0, 0);
            }
        }

        // (no mid-step barrier: reads hit buf[s&1], writes hit buf[s^1])

        // Whx/bh in-loop (anti-LICM: hoisting costs 32 regs -> spill).
        const float* wbp = Whx;
        const float* bbp = bh;
        asm volatile("" : "+v"(wbp), "+v"(bbp));

        // ---- epilogue: tanh, write h(s+1) in B-frag layout ----
        // C layout: col n = lane&15, row m = w*64 + mt*16 + q*4 + r.
#pragma unroll
        for (int mt = 0; mt < 4; ++mt) {
            int m0 = w * 64 + mt * 16 + q * 4;
            f32x4 whx4 = *(const f32x4*)(wbp + m0);
            f32x4 bh4  = *(const f32x4*)(bbp + m0);
            f16x4 hv;
#pragma unroll
            for (int r = 0; r < 4; ++r) {
                float pre = acc[mt][r] + whx4[r] * xv + bh4[r];
                hv[r] = (f16)fast_tanh(pre);
            }
            int kkd = w * 2 + (mt >> 1);
            int q2  = (mt & 1) * 2 + (q >> 1);
            int j0  = (q & 1) * 4;
            int off = (kkd * 64 + q2 * 16 + n) * 8 + j0;
            if (s < SEQT - 1) {
                *(f16x4*)&hbw[off] = hv;
            } else {
                *(f16x4*)(hG + (size_t)(((bg * 16 + kkd) * 64 + q2 * 16 + n) * 8 + j0)) = hv;
            }
        }

        // ---- pre-barrier W prefetch: WL is never written in-loop, so
        // chunk-0's reads are barrier-independent; they complete during
        // the drain and the next loop-head starts with W resident. ----
        if (s < SEQT - 1) {
#pragma unroll
            for (int mt = 0; mt < 4; ++mt)
                wg[mt] = *(const f16x8*)&WL[(((w * 4 + mt) * 4 + 0) * 64 + lane) * 8];
        }

        __syncthreads();   // h(s+1) writes visible before next step's reads
    }
}

// out[b][o] = by[o] + sum_k Wyh[o][k] * h[b][k], h in frag-blocked layout.
__global__ __launch_bounds__(256) void y_kernel(
    const f16* __restrict__ h, const float* __restrict__ Wyh,
    const float* __restrict__ by, float* __restrict__ out)
{
    int id = blockIdx.x * blockDim.x + threadIdx.x;
    if (id >= BATCH * OUTD) return;
    int b = id / OUTD, o = id % OUTD;
    int bg = b >> 4, n = b & 15;
    const float* wrow = Wyh + (size_t)o * HID;
    float s = by[o];
    for (int kk = 0; kk < 16; ++kk)
#pragma unroll
        for (int q2 = 0; q2 < 4; ++q2) {
            f16x8 hv = *(const f16x8*)(h + (size_t)((bg * 16 + kk) * 64 + q2 * 16 + n) * 8);
            const float* wp = wrow + kk * 32 + q2 * 8;
#pragma unroll
            for (int j = 0; j < 8; ++j) s += wp[j] * (float)hv[j];
        }
    out[id] = s;
}

extern "C" void kernel_launch(void* const* d_in, const int* in_sizes, int n_in,
                              void* d_out, int out_size, void* d_ws, size_t ws_size,
                              hipStream_t stream) {
    const float* x   = (const float*)d_in[0];
    const float* Whx = (const float*)d_in[1];
    const float* Whh = (const float*)d_in[2];
    const float* Wyh = (const float*)d_in[3];
    const float* bh  = (const float*)d_in[4];
    const float* by  = (const float*)d_in[5];
    float* out = (float*)d_out;

    char* ws   = (char*)d_ws;
    f16*  hG   = (f16*)ws;                       // 1 MB
    f16*  frag = (f16*)(ws + (2 << 20));         // 512 KB

    wconv_kernel<<<128, 256, 0, stream>>>(Whh, frag);
    rnn_cu<<<64, 512, 0, stream>>>(frag, hG, x, Whx, bh);
    y_kernel<<<(BATCH * OUTD + 255) / 256, 256, 0, stream>>>(hG, Wyh, by, out);
}

// Round 18
// 1255.039 us; speedup vs baseline: 1.0239x; 1.0239x over previous
//
#include <hip/hip_runtime.h>

// VanillaRNN: BATCH=1024, SEQ=512, HID=512, OUT=10
// h <- tanh(W_hh @ h + W_hx x_t + b_h), 512 steps, then y = W_yh h + b_y.
//
// FINAL (Round 22) = the session champion (R13/R20, 1208-1217us).
// Eleven mechanisms tested; the only win is this pipe-duty interleave
// (+5% over the R4 phase-split). Falsified with counters: W-from-global
// (R5 +36%), cross-CU M-split (R9 11x), 1-wave/SIMD ILP (R10 +30%),
// dataflow flags (R11 2x), LDS-funded read-ahead (R12 spill / R14 null),
// AGPR pinning (R15/R16 silent corruption -- inline-asm MFMA bypasses the
// hazard recognizer), wave desync (R19 clean null), cross-barrier W
// prefetch (R21: 16 transient regs -> spill, -3%).
// Structural floor: W-residency (512KB/CU) = regfile+LDS budget -> no
// registers for pipelining state -> ds_read latency exposed behind 2-wave
// TLP; step ~ DS-busy(3072cyc) + exposed latency + serial epilogue.
//
// Structure: 64 WGs x 8 waves, W CU-resident (Wr 48 frags/wave in regs +
// kk 12..15 in 128KB LDS), single HB + 2 barriers, interleaved kk order
// spreading the 4 LDS-W chunks evenly: ord={12,0,1,2,13,3,4,5,...}.
//
// ws: [0,1MB) hG (final h, frag-blocked) | [2MB,2.5MB) W A-frags.

#define BATCH 1024
#define SEQT  512
#define HID   512
#define OUTD  10
#define KR    12   // kk-blocks (of K=32) in registers: K=384
#define NKK   16

typedef _Float16 f16;
typedef _Float16 f16x8 __attribute__((ext_vector_type(8)));
typedef _Float16 f16x4 __attribute__((ext_vector_type(4)));
typedef float    f32x4 __attribute__((ext_vector_type(4)));

// W_hh fp32 [H][H] -> fp16 A-fragment layout:
// entry ((g*4+mt)*16+kk)*64+lane = f16x8 of A[m][k],
// m = g*64+mt*16+(lane&15), k = kk*32+((lane>>4)&3)*8+j.
__global__ void wconv_kernel(const float* __restrict__ Whh, f16* __restrict__ frag) {
    int id = blockIdx.x * blockDim.x + threadIdx.x;   // 0..32767
    int lane = id & 63;
    int kk   = (id >> 6) & 15;
    int mt   = (id >> 10) & 3;
    int g    = id >> 12;
    int m = g * 64 + mt * 16 + (lane & 15);
    int k = kk * 32 + ((lane >> 4) & 3) * 8;
    const float* src = Whh + (size_t)m * HID + k;
    f16x8 v;
#pragma unroll
    for (int j = 0; j < 8; ++j) v[j] = (f16)src[j];
    *(f16x8*)(frag + (size_t)id * 8) = v;
}

__device__ __forceinline__ float fast_tanh(float v) {
    v = fminf(fmaxf(v, -15.f), 15.f);
    float e = __expf(2.f * v);
    return (e - 1.f) * __builtin_amdgcn_rcpf(e + 1.f);
}

__global__ __launch_bounds__(512)
__attribute__((amdgpu_waves_per_eu(2, 2)))
void rnn_cu(
    const f16* __restrict__ frag,   // W_hh A-frags (all 16 kk-blocks)
    f16* __restrict__ hG,           // final h, frag-blocked [64][16][64][8]
    const float* __restrict__ x,    // [B][T]
    const float* __restrict__ Whx,  // [H]
    const float* __restrict__ bh)   // [H]
{
    // HB first: its ds offsets (<16 KB) fit the 16-bit imm with lane-only base.
    __shared__ f16 HB[8192];                    // h, B-frag layout, 16 KB
    __shared__ f16 WL[65536];                   // W A-frags kk 12..15, 128 KB

    const int tid  = threadIdx.x;
    const int w    = tid >> 6;       // wave = row-group of 64 rows
    const int lane = tid & 63;
    const int n    = lane & 15;      // batch col within group
    const int q    = lane >> 4;
    const int bg   = blockIdx.x;     // batch group: cols [bg*16, +16)

    // ---- h(0) = 0 ----
    {
        f16x8 z;
#pragma unroll
        for (int j = 0; j < 8; ++j) z[j] = (f16)0.f;
        *(f16x8*)&HB[tid * 16]     = z;
        *(f16x8*)&HB[tid * 16 + 8] = z;
    }

    const f16x8* A = (const f16x8*)frag;

    // ---- LDS W portion: wave w stages its (mt, kk 12..15) frags ----
#pragma unroll
    for (int mt = 0; mt < 4; ++mt)
#pragma unroll
        for (int kkl = 0; kkl < 4; ++kkl) {
            int e = ((w * 4 + mt) * 4 + kkl) * 64 + lane;
            *(f16x8*)&WL[e * 8] = A[((w * 4 + mt) * 16 + (KR + kkl)) * 64 + lane];
        }

    // ---- register W portion: kk 0..11, kk-major, static indices ----
    f16x8 Wr[KR * 4];
#pragma unroll
    for (int kk = 0; kk < KR; ++kk)
#pragma unroll
        for (int mt = 0; mt < 4; ++mt)
            Wr[kk * 4 + mt] = A[((w * 4 + mt) * 16 + kk) * 64 + lane];

    __syncthreads();

    const int b = bg * 16 + n;
    const float* xp = x + (size_t)b * SEQT;

#pragma unroll 1
    for (int s = 0; s < SEQT; ++s) {
        float xv = xp[s];

        f32x4 acc[4] = {{0,0,0,0},{0,0,0,0},{0,0,0,0},{0,0,0,0}};

        // ---- interleaved schedule: one LDS-W block per 4-slot chunk ----
        // t%4==0 -> tail block kk=12+(t>>2) (W from WL: 4 reads + 1 h read)
        // else   -> reg block rb=t-1-(t>>2)  (W from Wr: 1 h read)
#pragma unroll
        for (int t = 0; t < NKK; ++t) {
            constexpr int ord[NKK] = {12, 0, 1, 2, 13, 3, 4, 5,
                                      14, 6, 7, 8, 15, 9, 10, 11};
            const int kb = ord[t];
            f16x8 bf = *(const f16x8*)&HB[(kb * 64 + lane) * 8];
            if ((t & 3) == 0) {
                const int kkl = t >> 2;
#pragma unroll
                for (int mt = 0; mt < 4; ++mt) {
                    f16x8 a = *(const f16x8*)&WL[(((w * 4 + mt) * 4 + kkl) * 64 + lane) * 8];
                    acc[mt] = __builtin_amdgcn_mfma_f32_16x16x32_f16(
                        a, bf, acc[mt], 0, 0, 0);
                }
            } else {
                const int rb = t - 1 - (t >> 2);
#pragma unroll
                for (int mt = 0; mt < 4; ++mt)
                    acc[mt] = __builtin_amdgcn_mfma_f32_16x16x32_f16(
                        Wr[rb * 4 + mt], bf, acc[mt], 0, 0, 0);
            }
        }

        __syncthreads();   // all reads of h(s) done before in-place overwrite

        // Block loop-invariant hoisting of Whx/bh (would cost 32 VGPRs and
        // push past the 256 budget -> spill).
        const float* wbp = Whx;
        const float* bbp = bh;
        asm volatile("" : "+v"(wbp), "+v"(bbp));

        // ---- epilogue: tanh, write h(s+1) in B-frag layout ----
        // C layout: col n = lane&15, row m = w*64 + mt*16 + q*4 + r.
#pragma unroll
        for (int mt = 0; mt < 4; ++mt) {
            int m0 = w * 64 + mt * 16 + q * 4;
            f32x4 whx4 = *(const f32x4*)(wbp + m0);
            f32x4 bh4  = *(const f32x4*)(bbp + m0);
            f16x4 hv;
#pragma unroll
            for (int r = 0; r < 4; ++r) {
                float pre = acc[mt][r] + whx4[r] * xv + bh4[r];
                hv[r] = (f16)fast_tanh(pre);
            }
            int kkd = w * 2 + (mt >> 1);
            int q2  = (mt & 1) * 2 + (q >> 1);
            int j0  = (q & 1) * 4;
            int off = (kkd * 64 + q2 * 16 + n) * 8 + j0;
            if (s < SEQT - 1) {
                *(f16x4*)&HB[off] = hv;
            } else {
                *(f16x4*)(hG + (size_t)(((bg * 16 + kkd) * 64 + q2 * 16 + n) * 8 + j0)) = hv;
            }
        }

        __syncthreads();   // h(s+1) complete before next step's reads
    }
}

// out[b][o] = by[o] + sum_k Wyh[o][k] * h[b][k], h in frag-blocked layout.
__global__ __launch_bounds__(256) void y_kernel(
    const f16* __restrict__ h, const float* __restrict__ Wyh,
    const float* __restrict__ by, float* __restrict__ out)
{
    int id = blockIdx.x * blockDim.x + threadIdx.x;
    if (id >= BATCH * OUTD) return;
    int b = id / OUTD, o = id % OUTD;
    int bg = b >> 4, n = b & 15;
    const float* wrow = Wyh + (size_t)o * HID;
    float s = by[o];
    for (int kk = 0; kk < 16; ++kk)
#pragma unroll
        for (int q2 = 0; q2 < 4; ++q2) {
            f16x8 hv = *(const f16x8*)(h + (size_t)((bg * 16 + kk) * 64 + q2 * 16 + n) * 8);
            const float* wp = wrow + kk * 32 + q2 * 8;
#pragma unroll
            for (int j = 0; j < 8; ++j) s += wp[j] * (float)hv[j];
        }
    out[id] = s;
}

extern "C" void kernel_launch(void* const* d_in, const int* in_sizes, int n_in,
                              void* d_out, int out_size, void* d_ws, size_t ws_size,
                              hipStream_t stream) {
    const float* x   = (const float*)d_in[0];
    const float* Whx = (const float*)d_in[1];
    const float* Whh = (const float*)d_in[2];
    const float* Wyh = (const float*)d_in[3];
    const float* bh  = (const float*)d_in[4];
    const float* by  = (const float*)d_in[5];
    float* out = (float*)d_out;

    char* ws   = (char*)d_ws;
    f16*  hG   = (f16*)ws;                       // 1 MB
    f16*  frag = (f16*)(ws + (2 << 20));         // 512 KB

    wconv_kernel<<<128, 256, 0, stream>>>(Whh, frag);
    rnn_cu<<<64, 512, 0, stream>>>(frag, hG, x, Whx, bh);
    y_kernel<<<(BATCH * OUTD + 255) / 256, 256, 0, stream>>>(hG, Wyh, by, out);
}

// Round 19
// 1126.085 us; speedup vs baseline: 1.1411x; 1.1145x over previous
//
#include <hip/hip_runtime.h>

// VanillaRNN: BATCH=1024, SEQ=512, HID=512, OUT=10
// h <- tanh(W_hh @ h + W_hx x_t + b_h), 512 steps, then y = W_yh h + b_y.
//
// Round 23: champion (R13/R20/R22, 1223us dispatch) + Y-FUSION.
// Wall time 1255us vs dispatch 1223us -> ~32us is y_kernel (launch + 1MB
// hG readback) + the 1MB hG store (= rnn_cu's entire WRITE_SIZE). At
// s=511 each WG already holds ALL 512 rows of h for its 16 batch cols in
// HB -> after the final barrier, 160 threads/WG compute the 16x10 outputs
// directly from LDS (64 ds_read_b128 + 512 MACs each; Wyh 20KB, L2-hot).
// Main loop untouched (the proven interleaved schedule); hG + y_kernel
// deleted. Gate: WRITE_SIZE should collapse 1024KB -> ~64KB.
//
// Session ledger (for the record): the only in-kernel win was R13's
// pipe-duty interleave (+5%). Falsified with counters: W-from-global,
// cross-CU M-split, 1-wave ILP, dataflow flags, LDS-funded read-ahead x2,
// AGPR pinning x2 (inline-asm MFMA bypasses the hazard recognizer ->
// silent corruption), wave desync, cross-barrier W-prefetch. Structural
// floor: W-residency (512KB/CU) == regfile budget -> no registers for
// latency-hiding state; step ~ DS-busy + exposed ds_read latency.
//
// ws: [1MB,1.5MB) W A-frags (hG no longer needed).

#define BATCH 1024
#define SEQT  512
#define HID   512
#define OUTD  10
#define KR    12   // kk-blocks (of K=32) in registers: K=384
#define NKK   16

typedef _Float16 f16;
typedef _Float16 f16x8 __attribute__((ext_vector_type(8)));
typedef _Float16 f16x4 __attribute__((ext_vector_type(4)));
typedef float    f32x4 __attribute__((ext_vector_type(4)));

// W_hh fp32 [H][H] -> fp16 A-fragment layout:
// entry ((g*4+mt)*16+kk)*64+lane = f16x8 of A[m][k],
// m = g*64+mt*16+(lane&15), k = kk*32+((lane>>4)&3)*8+j.
__global__ void wconv_kernel(const float* __restrict__ Whh, f16* __restrict__ frag) {
    int id = blockIdx.x * blockDim.x + threadIdx.x;   // 0..32767
    int lane = id & 63;
    int kk   = (id >> 6) & 15;
    int mt   = (id >> 10) & 3;
    int g    = id >> 12;
    int m = g * 64 + mt * 16 + (lane & 15);
    int k = kk * 32 + ((lane >> 4) & 3) * 8;
    const float* src = Whh + (size_t)m * HID + k;
    f16x8 v;
#pragma unroll
    for (int j = 0; j < 8; ++j) v[j] = (f16)src[j];
    *(f16x8*)(frag + (size_t)id * 8) = v;
}

__device__ __forceinline__ float fast_tanh(float v) {
    v = fminf(fmaxf(v, -15.f), 15.f);
    float e = __expf(2.f * v);
    return (e - 1.f) * __builtin_amdgcn_rcpf(e + 1.f);
}

__global__ __launch_bounds__(512)
__attribute__((amdgpu_waves_per_eu(2, 2)))
void rnn_cu(
    const f16* __restrict__ frag,   // W_hh A-frags (all 16 kk-blocks)
    const float* __restrict__ x,    // [B][T]
    const float* __restrict__ Whx,  // [H]
    const float* __restrict__ bh,   // [H]
    const float* __restrict__ Wyh,  // [OUT][H]
    const float* __restrict__ by,   // [OUT]
    float* __restrict__ out)        // [B][OUT]
{
    // HB first: its ds offsets (<16 KB) fit the 16-bit imm with lane-only base.
    __shared__ f16 HB[8192];                    // h, B-frag layout, 16 KB
    __shared__ f16 WL[65536];                   // W A-frags kk 12..15, 128 KB

    const int tid  = threadIdx.x;
    const int w    = tid >> 6;       // wave = row-group of 64 rows
    const int lane = tid & 63;
    const int n    = lane & 15;      // batch col within group
    const int q    = lane >> 4;
    const int bg   = blockIdx.x;     // batch group: cols [bg*16, +16)

    // ---- h(0) = 0 ----
    {
        f16x8 z;
#pragma unroll
        for (int j = 0; j < 8; ++j) z[j] = (f16)0.f;
        *(f16x8*)&HB[tid * 16]     = z;
        *(f16x8*)&HB[tid * 16 + 8] = z;
    }

    const f16x8* A = (const f16x8*)frag;

    // ---- LDS W portion: wave w stages its (mt, kk 12..15) frags ----
#pragma unroll
    for (int mt = 0; mt < 4; ++mt)
#pragma unroll
        for (int kkl = 0; kkl < 4; ++kkl) {
            int e = ((w * 4 + mt) * 4 + kkl) * 64 + lane;
            *(f16x8*)&WL[e * 8] = A[((w * 4 + mt) * 16 + (KR + kkl)) * 64 + lane];
        }

    // ---- register W portion: kk 0..11, kk-major, static indices ----
    f16x8 Wr[KR * 4];
#pragma unroll
    for (int kk = 0; kk < KR; ++kk)
#pragma unroll
        for (int mt = 0; mt < 4; ++mt)
            Wr[kk * 4 + mt] = A[((w * 4 + mt) * 16 + kk) * 64 + lane];

    __syncthreads();

    const int b = bg * 16 + n;
    const float* xp = x + (size_t)b * SEQT;

#pragma unroll 1
    for (int s = 0; s < SEQT; ++s) {
        float xv = xp[s];

        f32x4 acc[4] = {{0,0,0,0},{0,0,0,0},{0,0,0,0},{0,0,0,0}};

        // ---- interleaved schedule: one LDS-W block per 4-slot chunk ----
        // t%4==0 -> tail block kk=12+(t>>2) (W from WL: 4 reads + 1 h read)
        // else   -> reg block rb=t-1-(t>>2)  (W from Wr: 1 h read)
#pragma unroll
        for (int t = 0; t < NKK; ++t) {
            constexpr int ord[NKK] = {12, 0, 1, 2, 13, 3, 4, 5,
                                      14, 6, 7, 8, 15, 9, 10, 11};
            const int kb = ord[t];
            f16x8 bf = *(const f16x8*)&HB[(kb * 64 + lane) * 8];
            if ((t & 3) == 0) {
                const int kkl = t >> 2;
#pragma unroll
                for (int mt = 0; mt < 4; ++mt) {
                    f16x8 a = *(const f16x8*)&WL[(((w * 4 + mt) * 4 + kkl) * 64 + lane) * 8];
                    acc[mt] = __builtin_amdgcn_mfma_f32_16x16x32_f16(
                        a, bf, acc[mt], 0, 0, 0);
                }
            } else {
                const int rb = t - 1 - (t >> 2);
#pragma unroll
                for (int mt = 0; mt < 4; ++mt)
                    acc[mt] = __builtin_amdgcn_mfma_f32_16x16x32_f16(
                        Wr[rb * 4 + mt], bf, acc[mt], 0, 0, 0);
            }
        }

        __syncthreads();   // all reads of h(s) done before in-place overwrite

        // Block loop-invariant hoisting of Whx/bh (would cost 32 VGPRs and
        // push past the 256 budget -> spill).
        const float* wbp = Whx;
        const float* bbp = bh;
        asm volatile("" : "+v"(wbp), "+v"(bbp));

        // ---- epilogue: tanh, write h(s+1) in B-frag layout (always HB;
        //      the final h stays in LDS for the fused y phase) ----
        // C layout: col n = lane&15, row m = w*64 + mt*16 + q*4 + r.
#pragma unroll
        for (int mt = 0; mt < 4; ++mt) {
            int m0 = w * 64 + mt * 16 + q * 4;
            f32x4 whx4 = *(const f32x4*)(wbp + m0);
            f32x4 bh4  = *(const f32x4*)(bbp + m0);
            f16x4 hv;
#pragma unroll
            for (int r = 0; r < 4; ++r) {
                float pre = acc[mt][r] + whx4[r] * xv + bh4[r];
                hv[r] = (f16)fast_tanh(pre);
            }
            int kkd = w * 2 + (mt >> 1);
            int q2  = (mt & 1) * 2 + (q >> 1);
            int j0  = (q & 1) * 4;
            *(f16x4*)&HB[(kkd * 64 + q2 * 16 + n) * 8 + j0] = hv;
        }

        __syncthreads();   // h(s+1) complete before next step's reads
    }

    // ---- fused y: out[b][o] = by[o] + sum_m Wyh[o][m] * h[m][b].
    // h(SEQT) for this WG's 16 cols is fully resident in HB:
    // h[m][col nn] = HB[((m>>5)*64 + ((m>>3)&3)*16 + nn)*8 + (m&7)].
    // 160 threads: nn = tid&15, o = tid>>4. Wyh rows are 2KB, L2-hot.
    if (tid < 16 * OUTD) {
        const int nn = tid & 15;
        const int o  = tid >> 4;
        const float* wrow = Wyh + (size_t)o * HID;
        float sum = by[o];
        for (int kk = 0; kk < 16; ++kk)
#pragma unroll
            for (int q2 = 0; q2 < 4; ++q2) {
                f16x8 hv = *(const f16x8*)&HB[((kk * 64 + q2 * 16 + nn)) * 8];
                const float* wp = wrow + kk * 32 + q2 * 8;
#pragma unroll
                for (int j = 0; j < 8; ++j) sum += wp[j] * (float)hv[j];
            }
        out[(size_t)(bg * 16 + nn) * OUTD + o] = sum;
    }
}

extern "C" void kernel_launch(void* const* d_in, const int* in_sizes, int n_in,
                              void* d_out, int out_size, void* d_ws, size_t ws_size,
                              hipStream_t stream) {
    const float* x   = (const float*)d_in[0];
    const float* Whx = (const float*)d_in[1];
    const float* Whh = (const float*)d_in[2];
    const float* Wyh = (const float*)d_in[3];
    const float* bh  = (const float*)d_in[4];
    const float* by  = (const float*)d_in[5];
    float* out = (float*)d_out;

    char* ws   = (char*)d_ws;
    f16*  frag = (f16*)(ws + (1 << 20));         // 512 KB @ 1MB

    wconv_kernel<<<128, 256, 0, stream>>>(Whh, frag);
    rnn_cu<<<64, 512, 0, stream>>>(frag, x, Whx, bh, Wyh, by, out);
}